// Round 7
// baseline (124.442 us; speedup 1.0000x reference)
//
#include <hip/hip_runtime.h>
#include <hip/hip_bf16.h>
#include <cstddef>
#include <cstdint>

// LSTMCell fused: z = [u|h] @ [W|U]^T + bW + bE ; gates ; c/h update.
// fp32 in / fp32 out; bf16 MFMA internal, fp32 accum.
// R7: W-operand DIRECT global->VGPR (no W LDS) — cuts LDS pipe from 3072 to
//     1920 cyc/block-tile, below the MFMA pipe (2484 cyc) -> MFMA-bound.
//     W slice (512 KB/XCD) is L2-resident via XCD swizzle; B-frag pattern
//     (col=l&15, k=(l>>4)*8) = 16x64B segments/instr, offset-folded from 4
//     base pointers. W(t,kk+1) issued one half-tile early; compiler handles
//     vmcnt (R6 lesson: manual schedule machinery regressed).
//     A stays global_load_lds-staged, 2x32KB dbuf, R5's proven 2-barrier loop.
// Pre-pass: X=[u|h]->bf16 (32MB), W gate-major bf16 (4MB), combined bias.

#define BDIM 16384
#define HDIM 512

typedef __attribute__((ext_vector_type(8))) short bf16x8;
typedef __attribute__((ext_vector_type(4))) float f32x4;

struct Params {
  const float* u;
  const float* h;
  const float* c;
  const float* W[4];
  const float* U[4];
  const float* bW[4];
  const float* bE[4];
  float* outh;
  float* outc;
};

__device__ __forceinline__ float sigmoidf_(float x) {
  return 1.0f / (1.0f + __expf(-x));
}
__device__ __forceinline__ float tanhf_(float x) {
  return 2.0f / (1.0f + __expf(-2.0f * x)) - 1.0f;
}

__device__ __forceinline__ void async16(const void* g, void* l) {
  __builtin_amdgcn_global_load_lds((const __attribute__((address_space(1))) void*)g,
                                   (__attribute__((address_space(3))) void*)l,
                                   16, 0, 0);
}

__device__ __forceinline__ bf16x8 cvt8(f32x4 a, f32x4 b) {
  bf16x8 r;
#pragma unroll
  for (int j = 0; j < 4; ++j) {
    __hip_bfloat16 t = __float2bfloat16(a[j]);
    r[j] = *reinterpret_cast<short*>(&t);
  }
#pragma unroll
  for (int j = 0; j < 4; ++j) {
    __hip_bfloat16 t = __float2bfloat16(b[j]);
    r[4 + j] = *reinterpret_cast<short*>(&t);
  }
  return r;
}

// ---------- pre-pass 1: X = [u|h] -> bf16 [16384][1024] ----------
__global__ void cvt_x_kernel(const float* __restrict__ u, const float* __restrict__ h,
                             __hip_bfloat16* __restrict__ Xbf) {
  const size_t e = ((size_t)blockIdx.x * 512 + threadIdx.x) * 8;
  const int r = (int)(e >> 10);
  const int cidx = (int)(e & 1023);
  const float* s = (cidx < 512) ? (u + (size_t)r * 512 + cidx)
                                : (h + (size_t)r * 512 + (cidx - 512));
  f32x4 v0 = *(const f32x4*)s;
  f32x4 v1 = *(const f32x4*)(s + 4);
  *(bf16x8*)(Xbf + e) = cvt8(v0, v1);
}

// ---------- pre-pass 2: Wbf[g][hcol][k'] bf16 + combined bias ----------
__global__ void cvt_w_kernel(Params p, __hip_bfloat16* __restrict__ Wbf,
                             float* __restrict__ biasC) {
  const size_t gt = (size_t)blockIdx.x * 512 + threadIdx.x;
  const size_t e = gt * 8;
  const int g = (int)(e >> 19);
  const int rem = (int)(e & 524287);
  const int hcol = rem >> 10;
  const int k = rem & 1023;
  const float* s = (k < 512) ? (p.W[g] + (size_t)hcol * 512 + k)
                             : (p.U[g] + (size_t)hcol * 512 + (k - 512));
  f32x4 v0 = *(const f32x4*)s;
  f32x4 v1 = *(const f32x4*)(s + 4);
  *(bf16x8*)(Wbf + e) = cvt8(v0, v1);
  if (gt < 2048) {
    const int bg = (int)(gt >> 9), hh = (int)(gt & 511);
    biasC[gt] = p.bW[bg][hh] + p.bE[bg][hh];
  }
}

// ---------- main GEMM + fused gates ----------
__launch_bounds__(512, 2)
__global__ void lstm_main_kernel(const __hip_bfloat16* __restrict__ Xbf,
                                 const __hip_bfloat16* __restrict__ Wbf,
                                 const float* __restrict__ biasC,
                                 const float* __restrict__ c,
                                 float* __restrict__ outh,
                                 float* __restrict__ outc) {
  // LDS: A only, 2 bufs x [256][64] bf16 = 64 KB
  __shared__ char smem[65536];

  const int tid = threadIdx.x;
  const int w   = tid >> 6;   // 0..7
  const int l   = tid & 63;
  const int wm  = w >> 2;     // 0..1 : 128-row half
  const int wh  = w & 3;      // 0..3 : 16-hcol group

  // XCD swizzle: 512 blocks, 8 XCDs -> XCD x owns h_tile x (512 KB L2 slice)
  const int swz = (blockIdx.x & 7) * 64 + (blockIdx.x >> 3);
  const int m_tile = swz & 63;
  const int h_tile = swz >> 6;
  const int rowA0 = m_tile * 256;
  const int nrow0 = h_tile * 64;

  const int rsub = l >> 3;             // 0..7 row-within-8
  const int slot = (l & 7) ^ rsub;     // pre-swizzled source 16B slot

  // A staging source pointers (advance 64 bf16 = 128 B per K-tile)
  const __hip_bfloat16* gpA[4];
#pragma unroll
  for (int j = 0; j < 4; ++j)
    gpA[j] = Xbf + (size_t)(rowA0 + w * 32 + j * 8 + rsub) * 1024 + slot * 8;

  // W fragment base pointers: 4 gates; frag(t,kk) at +t*64 + kk*32 elems
  // B-frag layout: col = l&15 (hcol row of Wbf), k = (l>>4)*8 contiguous
  const __hip_bfloat16* wp[4];
#pragma unroll
  for (int g = 0; g < 4; ++g)
    wp[g] = Wbf + (size_t)(g * 512 + nrow0 + wh * 16 + (l & 15)) * 1024 + (l >> 4) * 8;

  f32x4 acc[4][8] = {};  // [gate][m-frag]

  const int xr = (l & 7) << 4;     // read-side LDS swizzle
  const int ar = l & 15;           // fragment row-within-16
  const int kbase = (l >> 4) * 16;

#define STAGE_A(T)                                                        \
  {                                                                       \
    char* db = smem + (((T) & 1) << 15);                                  \
    _Pragma("unroll") for (int j = 0; j < 4; ++j)                         \
        async16(gpA[j] + (T) * 64, db + (w * 32 + j * 8) * 128);          \
  }

  // prologue: W(0,0) frags + A tile 0
  bf16x8 wa[4], wb[4];
#pragma unroll
  for (int g = 0; g < 4; ++g) wa[g] = *(const bf16x8*)(wp[g]);
  STAGE_A(0)
  __syncthreads();

  for (int t = 0; t < 16; ++t) {
    const char* bufA = smem + ((t & 1) << 15);
    if (t < 15) STAGE_A(t + 1)

    // ---- kk = 0 : prefetch W(t,1), read A kk0, MFMA with wa ----
#pragma unroll
    for (int g = 0; g < 4; ++g)
      wb[g] = *(const bf16x8*)(wp[g] + t * 64 + 32);
    {
      const int kb = kbase ^ xr;
      bf16x8 av[8];
#pragma unroll
      for (int mf = 0; mf < 8; ++mf)
        av[mf] = *(const bf16x8*)(bufA + (wm * 128 + mf * 16 + ar) * 128 + kb);
#pragma unroll
      for (int g = 0; g < 4; ++g)
#pragma unroll
        for (int mf = 0; mf < 8; ++mf)
          acc[g][mf] = __builtin_amdgcn_mfma_f32_16x16x32_bf16(av[mf], wa[g], acc[g][mf], 0, 0, 0);
    }
    // ---- kk = 1 : prefetch W(t+1,0), read A kk1, MFMA with wb ----
    if (t < 15) {
#pragma unroll
      for (int g = 0; g < 4; ++g)
        wa[g] = *(const bf16x8*)(wp[g] + (t + 1) * 64);
    }
    {
      const int kb = (64 + kbase) ^ xr;
      bf16x8 av[8];
#pragma unroll
      for (int mf = 0; mf < 8; ++mf)
        av[mf] = *(const bf16x8*)(bufA + (wm * 128 + mf * 16 + ar) * 128 + kb);
#pragma unroll
      for (int g = 0; g < 4; ++g)
#pragma unroll
        for (int mf = 0; mf < 8; ++mf)
          acc[g][mf] = __builtin_amdgcn_mfma_f32_16x16x32_bf16(av[mf], wb[g], acc[g][mf], 0, 0, 0);
    }
    __syncthreads();  // A reads done; next tile's stage (issued above) visible
  }
#undef STAGE_A

  // ---- fused epilogue ----
  // C/D layout: col = lane&15, row = (lane>>4)*4 + reg   [m89/m91]
  const int lr = (l >> 4) * 4;
  const int lc = l & 15;
  const int hc = nrow0 + wh * 16 + lc;
  const float bzi = biasC[0 * 512 + hc];
  const float bzf = biasC[1 * 512 + hc];
  const float bzg = biasC[2 * 512 + hc];
  const float bzo = biasC[3 * 512 + hc];
#pragma unroll
  for (int mf = 0; mf < 8; ++mf) {
#pragma unroll
    for (int j = 0; j < 4; ++j) {
      const int row = rowA0 + wm * 128 + mf * 16 + lr + j;
      const float zi = acc[0][mf][j] + bzi;
      const float zf = acc[1][mf][j] + bzf;
      const float zg = acc[2][mf][j] + bzg;
      const float zo = acc[3][mf][j] + bzo;
      const float ig = sigmoidf_(zi);
      const float fg = sigmoidf_(zf);
      const float gg = tanhf_(zg);
      const float og = sigmoidf_(zo);
      const size_t idx = (size_t)row * 512 + hc;
      const float cv = c[idx];
      const float cn = fg * cv + ig * gg;
      const float hn = og * tanhf_(cn);
      outh[idx] = hn;
      outc[idx] = cn;
    }
  }
}

// ---------- fallback: proven R2 kernel ----------
__launch_bounds__(256, 2)
__global__ void lstm_legacy_kernel(Params p) {
  __shared__ char smem[32768];
  __shared__ float biasLDS[4][32];

  const int tid = threadIdx.x;
  const int w   = tid >> 6;
  const int l   = tid & 63;
  const int m_tile = blockIdx.x & 127;
  const int h_tile = blockIdx.x >> 7;

  char* smemA = smem;
  char* smemW = smem + 16384;
  const int rowA0 = m_tile * 128;
  const int nrow0 = h_tile * 32;

  if (tid < 128) {
    const int g = tid >> 5, hh = tid & 31;
    const int hc = nrow0 + hh;
    biasLDS[g][hh] = p.bW[g][hc] + p.bE[g][hc];
  }

  const int sr = tid >> 3;
  const int sc = tid & 7;
  const int wcol = (sc * 16) ^ ((sr & 7) << 4);

  f32x4 acc[4][2][2] = {};
  f32x4 rg[16];

  auto load_tile = [&](int kt) {
    const float* sA = (kt < 8) ? p.u : p.h;
    const int kc = (kt & 7) * 64;
#pragma unroll
    for (int cc = 0; cc < 4; ++cc) {
      const float* gp = sA + (size_t)(rowA0 + cc * 32 + sr) * 512 + kc + sc * 8;
      rg[cc * 2]     = *(const f32x4*)gp;
      rg[cc * 2 + 1] = *(const f32x4*)(gp + 4);
    }
#pragma unroll
    for (int cc = 0; cc < 4; ++cc) {
      const float* sW = (kt < 8) ? p.W[cc] : p.U[cc];
      const float* gp = sW + (size_t)(nrow0 + sr) * 512 + kc + sc * 8;
      rg[8 + cc * 2]     = *(const f32x4*)gp;
      rg[8 + cc * 2 + 1] = *(const f32x4*)(gp + 4);
    }
  };

  auto write_tile = [&]() {
#pragma unroll
    for (int cc = 0; cc < 4; ++cc)
      *(bf16x8*)(smemA + (cc * 32 + sr) * 128 + wcol) = cvt8(rg[cc * 2], rg[cc * 2 + 1]);
#pragma unroll
    for (int cc = 0; cc < 4; ++cc)
      *(bf16x8*)(smemW + (cc * 32 + sr) * 128 + wcol) = cvt8(rg[8 + cc * 2], rg[8 + cc * 2 + 1]);
  };

  const int xr = (l & 7) << 4;

  auto compute = [&]() {
#pragma unroll
    for (int kk = 0; kk < 2; ++kk) {
      const int kb = (kk * 64 + (l >> 4) * 16) ^ xr;
      bf16x8 a0 = *(const bf16x8*)(smemA + (w * 32 +      (l & 15)) * 128 + kb);
      bf16x8 a1 = *(const bf16x8*)(smemA + (w * 32 + 16 + (l & 15)) * 128 + kb);
#pragma unroll
      for (int g = 0; g < 4; ++g) {
#pragma unroll
        for (int ni = 0; ni < 2; ++ni) {
          bf16x8 b = *(const bf16x8*)(smemW + (g * 32 + ni * 16 + (l & 15)) * 128 + kb);
          acc[g][0][ni] = __builtin_amdgcn_mfma_f32_16x16x32_bf16(a0, b, acc[g][0][ni], 0, 0, 0);
          acc[g][1][ni] = __builtin_amdgcn_mfma_f32_16x16x32_bf16(a1, b, acc[g][1][ni], 0, 0, 0);
        }
      }
    }
  };

  load_tile(0);
  for (int kt = 0; kt < 16; ++kt) {
    write_tile();
    __syncthreads();
    if (kt < 15) load_tile(kt + 1);
    compute();
    __syncthreads();
  }

  const int lr = (l >> 4) * 4;
  const int lc = l & 15;
#pragma unroll
  for (int mi = 0; mi < 2; ++mi) {
#pragma unroll
    for (int j = 0; j < 4; ++j) {
      const int row = rowA0 + w * 32 + mi * 16 + lr + j;
#pragma unroll
      for (int ni = 0; ni < 2; ++ni) {
        const int hc = nrow0 + ni * 16 + lc;
        const int bcol = ni * 16 + lc;
        const float zi = acc[0][mi][ni][j] + biasLDS[0][bcol];
        const float zf = acc[1][mi][ni][j] + biasLDS[1][bcol];
        const float zg = acc[2][mi][ni][j] + biasLDS[2][bcol];
        const float zo = acc[3][mi][ni][j] + biasLDS[3][bcol];
        const float ig = sigmoidf_(zi);
        const float fg = sigmoidf_(zf);
        const float gg = tanhf_(zg);
        const float og = sigmoidf_(zo);
        const size_t idx = (size_t)row * 512 + hc;
        const float cv = p.c[idx];
        const float cn = fg * cv + ig * gg;
        const float hn = og * tanhf_(cn);
        p.outh[idx] = hn;
        p.outc[idx] = cn;
      }
    }
  }
}

extern "C" void kernel_launch(void* const* d_in, const int* in_sizes, int n_in,
                              void* d_out, int out_size, void* d_ws, size_t ws_size,
                              hipStream_t stream) {
  Params p;
  p.u = (const float*)d_in[0];
  p.h = (const float*)d_in[1];
  p.c = (const float*)d_in[2];
  p.W[0] = (const float*)d_in[3];
  p.bW[0] = (const float*)d_in[4];
  p.W[1] = (const float*)d_in[5];
  p.bW[1] = (const float*)d_in[6];
  p.W[2] = (const float*)d_in[7];
  p.bW[2] = (const float*)d_in[8];
  p.W[3] = (const float*)d_in[9];
  p.bW[3] = (const float*)d_in[10];
  p.U[0] = (const float*)d_in[11];
  p.U[1] = (const float*)d_in[12];
  p.U[2] = (const float*)d_in[13];
  p.U[3] = (const float*)d_in[14];
  p.bE[0] = (const float*)d_in[15];
  p.bE[1] = (const float*)d_in[16];
  p.bE[2] = (const float*)d_in[17];
  p.bE[3] = (const float*)d_in[18];
  p.outh = (float*)d_out;
  p.outc = (float*)d_out + (size_t)BDIM * HDIM;

  const size_t X_BYTES = (size_t)BDIM * 1024 * 2;        // 32 MB
  const size_t W_BYTES = (size_t)4 * 512 * 1024 * 2;     // 4 MB
  const size_t B_BYTES = 2048 * 4;                       // 8 KB
  if (ws_size >= X_BYTES + W_BYTES + B_BYTES) {
    __hip_bfloat16* Xbf = (__hip_bfloat16*)d_ws;
    __hip_bfloat16* Wbf = (__hip_bfloat16*)((char*)d_ws + X_BYTES);
    float* biasC = (float*)((char*)d_ws + X_BYTES + W_BYTES);

    hipLaunchKernelGGL(cvt_x_kernel, dim3(4096), dim3(512), 0, stream, p.u, p.h, Xbf);
    hipLaunchKernelGGL(cvt_w_kernel, dim3(512), dim3(512), 0, stream, p, Wbf, biasC);
    hipLaunchKernelGGL(lstm_main_kernel, dim3(512), dim3(512), 0, stream,
                       Xbf, Wbf, biasC, p.c, p.outh, p.outc);
  } else {
    hipLaunchKernelGGL(lstm_legacy_kernel, dim3(2048), dim3(256), 0, stream, p);
  }
}

// Round 8
// 99.314 us; speedup vs baseline: 1.2530x; 1.2530x over previous
//
#include <hip/hip_runtime.h>
#include <hip/hip_bf16.h>
#include <cstddef>
#include <cstdint>

// LSTMCell fused: z = [u|h] @ [W|U]^T + bW + bE ; gates ; c/h update.
// fp32 in / fp32 out; bf16 MFMA internal, fp32 accum.
// R8: m201-style phased schedule with COUNTED vmcnt on R5 geometry.
//   BM=256 x (4 gates x 64 hcol), BK=64, 512 thr / 8 waves, 128 KB LDS dbuf.
//   Tile = 8 staged chunks (A: 4x64rows, W: 4 gates). Tile t's 4 phases stage
//   tile t+1's chunks in consumption order {A00,A10|W0,W1|W2,W3|A01,A11}.
//   Phase: vmcnt(4); s_barrier; ds_read quadrant; stage 2 chunks; lgkmcnt(0);
//   setprio(1); 16 MFMA; setprio(0).  vmcnt(4) provably completes exactly the
//   chunks the phase reads (prologue staged in same order => t=0 uniform).
//   Tail tile drains 4->2->0. Loads stay 4 chunks deep across barriers.
//   R7 lesson: vmcnt is one FIFO/wave — never put dependent VGPR loads behind
//   staging loads. R6 lesson: vmcnt(0)/tile + lockstep barriers = no overlap.
// Pre-pass: X=[u|h]->bf16 (32MB), W gate-major bf16 (4MB), combined bias.

#define BDIM 16384
#define HDIM 512

typedef __attribute__((ext_vector_type(8))) short bf16x8;
typedef __attribute__((ext_vector_type(4))) float f32x4;

struct Params {
  const float* u;
  const float* h;
  const float* c;
  const float* W[4];
  const float* U[4];
  const float* bW[4];
  const float* bE[4];
  float* outh;
  float* outc;
};

__device__ __forceinline__ float sigmoidf_(float x) {
  return 1.0f / (1.0f + __expf(-x));
}
__device__ __forceinline__ float tanhf_(float x) {
  return 2.0f / (1.0f + __expf(-2.0f * x)) - 1.0f;
}

__device__ __forceinline__ void async16(const void* g, void* l) {
  __builtin_amdgcn_global_load_lds((const __attribute__((address_space(1))) void*)g,
                                   (__attribute__((address_space(3))) void*)l,
                                   16, 0, 0);
}

__device__ __forceinline__ bf16x8 cvt8(f32x4 a, f32x4 b) {
  bf16x8 r;
#pragma unroll
  for (int j = 0; j < 4; ++j) {
    __hip_bfloat16 t = __float2bfloat16(a[j]);
    r[j] = *reinterpret_cast<short*>(&t);
  }
#pragma unroll
  for (int j = 0; j < 4; ++j) {
    __hip_bfloat16 t = __float2bfloat16(b[j]);
    r[4 + j] = *reinterpret_cast<short*>(&t);
  }
  return r;
}

// ---------- pre-pass 1: X = [u|h] -> bf16 [16384][1024] ----------
__global__ void cvt_x_kernel(const float* __restrict__ u, const float* __restrict__ h,
                             __hip_bfloat16* __restrict__ Xbf) {
  const size_t e = ((size_t)blockIdx.x * 512 + threadIdx.x) * 8;
  const int r = (int)(e >> 10);
  const int cidx = (int)(e & 1023);
  const float* s = (cidx < 512) ? (u + (size_t)r * 512 + cidx)
                                : (h + (size_t)r * 512 + (cidx - 512));
  f32x4 v0 = *(const f32x4*)s;
  f32x4 v1 = *(const f32x4*)(s + 4);
  *(bf16x8*)(Xbf + e) = cvt8(v0, v1);
}

// ---------- pre-pass 2: Wbf[g][hcol][k'] bf16 + combined bias ----------
__global__ void cvt_w_kernel(Params p, __hip_bfloat16* __restrict__ Wbf,
                             float* __restrict__ biasC) {
  const size_t gt = (size_t)blockIdx.x * 512 + threadIdx.x;
  const size_t e = gt * 8;
  const int g = (int)(e >> 19);
  const int rem = (int)(e & 524287);
  const int hcol = rem >> 10;
  const int k = rem & 1023;
  const float* s = (k < 512) ? (p.W[g] + (size_t)hcol * 512 + k)
                             : (p.U[g] + (size_t)hcol * 512 + (k - 512));
  f32x4 v0 = *(const f32x4*)s;
  f32x4 v1 = *(const f32x4*)(s + 4);
  *(bf16x8*)(Wbf + e) = cvt8(v0, v1);
  if (gt < 2048) {
    const int bg = (int)(gt >> 9), hh = (int)(gt & 511);
    biasC[gt] = p.bW[bg][hh] + p.bE[bg][hh];
  }
}

// ---------- main GEMM + fused gates: 4-phase counted-vmcnt schedule ----------
#define VM4 asm volatile("s_waitcnt vmcnt(4)" ::: "memory")
#define VM2 asm volatile("s_waitcnt vmcnt(2)" ::: "memory")
#define VM0 asm volatile("s_waitcnt vmcnt(0)" ::: "memory")
#define LG0 asm volatile("s_waitcnt lgkmcnt(0)" ::: "memory")
#define BARRIER do { __builtin_amdgcn_s_barrier(); asm volatile("" ::: "memory"); } while (0)
#define FENCE __builtin_amdgcn_sched_barrier(0)

#define READ_A(BUF, MH, DST)                                                         \
  _Pragma("unroll") for (int mf = 0; mf < 4; ++mf) {                                 \
    DST[mf * 2 + 0] = *(const bf16x8*)((BUF) + (wm * 128 + (MH) * 64 + mf * 16 + ar) * 128 + kb0); \
    DST[mf * 2 + 1] = *(const bf16x8*)((BUF) + (wm * 128 + (MH) * 64 + mf * 16 + ar) * 128 + kb1); \
  }
#define READ_W(BUF, GH, DST)                                                         \
  _Pragma("unroll") for (int g2 = 0; g2 < 2; ++g2) {                                 \
    DST[g2 * 2 + 0] = *(const bf16x8*)((BUF) + (((GH) * 2 + g2) * 64 + wh * 16 + ar) * 128 + kb0); \
    DST[g2 * 2 + 1] = *(const bf16x8*)((BUF) + (((GH) * 2 + g2) * 64 + wh * 16 + ar) * 128 + kb1); \
  }
#define MMAC(MH, GH, AF, BF)                                                         \
  do {                                                                               \
    __builtin_amdgcn_s_setprio(1);                                                   \
    _Pragma("unroll") for (int g2 = 0; g2 < 2; ++g2)                                 \
    _Pragma("unroll") for (int mf = 0; mf < 4; ++mf)                                 \
    _Pragma("unroll") for (int kk = 0; kk < 2; ++kk)                                 \
      acc[(GH) * 2 + g2][(MH) * 4 + mf] = __builtin_amdgcn_mfma_f32_16x16x32_bf16(   \
          AF[mf * 2 + kk], BF[g2 * 2 + kk], acc[(GH) * 2 + g2][(MH) * 4 + mf], 0, 0, 0); \
    __builtin_amdgcn_s_setprio(0);                                                   \
  } while (0)

__launch_bounds__(512, 2)
__global__ void lstm_main_kernel(const __hip_bfloat16* __restrict__ Xbf,
                                 const __hip_bfloat16* __restrict__ Wbf,
                                 const float* __restrict__ biasC,
                                 const float* __restrict__ c,
                                 float* __restrict__ outh,
                                 float* __restrict__ outc) {
  // 2 slots x (A [256][64] 32KB + W [256][64] 32KB) = 128 KB
  __shared__ char smem[131072];

  const int tid = threadIdx.x;
  const int w   = tid >> 6;   // 0..7
  const int l   = tid & 63;
  const int wm  = w >> 2;     // 0..1 : 128-row half
  const int wh  = w & 3;      // 0..3 : 16-hcol group

  const int swz = (blockIdx.x & 7) * 64 + (blockIdx.x >> 3);
  const int m_tile = swz & 63;
  const int h_tile = swz >> 6;
  const int rowA0 = m_tile * 256;
  const int nrow0 = h_tile * 64;

  const int rsub = l >> 3;             // row-within-8
  const int slot = (l & 7) ^ rsub;     // pre-swizzled source 16B slot
  const int wofs = w * 8 * 128;        // wave's row offset inside a 64-row chunk

  // per-thread staging bases (advance 64 elems = 128 B per K-tile)
  const __hip_bfloat16* pA = Xbf + (size_t)(rowA0 + w * 8 + rsub) * 1024 + slot * 8;
  const __hip_bfloat16* pW = Wbf + (size_t)(nrow0 + w * 8 + rsub) * 1024 + slot * 8;

  f32x4 acc[4][8] = {};  // [gate][m-frag]

  const int xr  = (l & 7) << 4;
  const int ar  = l & 15;
  const int kb0 = (((l >> 4) * 16)) ^ xr;
  const int kb1 = (64 + ((l >> 4) * 16)) ^ xr;

  // stage one 64-row chunk (1 async16/thread). A chunk (mh,r): rows mh*128+r*64.
  auto stA = [&](const __hip_bfloat16* base, char* sl, int mh, int r) {
    async16(base + (size_t)(mh * 128 + r * 64) * 1024,
            sl + (mh * 128 + r * 64) * 128 + wofs);
  };
  auto stW = [&](const __hip_bfloat16* base, char* sl, int g) {
    async16(base + (size_t)(g * 512) * 1024,
            sl + 32768 + g * 64 * 128 + wofs);
  };

  // prologue: stage tile 0 in consumption order (A00,A10,W0,W1,W2,W3,A01,A11)
  {
    char* s0 = smem;
    stA(pA, s0, 0, 0); stA(pA, s0, 1, 0);
    stW(pW, s0, 0);    stW(pW, s0, 1);
    stW(pW, s0, 2);    stW(pW, s0, 3);
    stA(pA, s0, 0, 1); stA(pA, s0, 1, 1);
  }

  bf16x8 aF[8], bLo[4], bHi[4];
  const __hip_bfloat16* npA = pA + 64;
  const __hip_bfloat16* npW = pW + 64;

  for (int t = 0; t < 15; ++t) {
    const char* bufA = smem + ((t & 1) << 16);
    const char* bufW = bufA + 32768;
    char* ns = smem + (((t + 1) & 1) << 16);

    // PH1: quadrant (mh0, gh0); stage A00,A10 of t+1
    VM4; BARRIER;
    READ_A(bufA, 0, aF);
    READ_W(bufW, 0, bLo);
    stA(npA, ns, 0, 0); stA(npA, ns, 1, 0);
    LG0; FENCE;
    MMAC(0, 0, aF, bLo); FENCE;

    // PH2: (mh0, gh1); stage W0,W1
    VM4; BARRIER;
    READ_W(bufW, 1, bHi);
    stW(npW, ns, 0); stW(npW, ns, 1);
    LG0; FENCE;
    MMAC(0, 1, aF, bHi); FENCE;

    // PH3: (mh1, gh0); stage W2,W3
    VM4; BARRIER;
    READ_A(bufA, 1, aF);
    stW(npW, ns, 2); stW(npW, ns, 3);
    LG0; FENCE;
    MMAC(1, 0, aF, bLo); FENCE;

    // PH4: (mh1, gh1); stage A01,A11 (no barrier/reads)
    stA(npA, ns, 0, 1); stA(npA, ns, 1, 1);
    MMAC(1, 1, aF, bHi); FENCE;

    npA += 64; npW += 64;
  }

  // tail tile 15 (slot 1): no stages; drain 4 -> 2 -> 0
  {
    const char* bufA = smem + (1 << 16);
    const char* bufW = bufA + 32768;
    VM4; BARRIER;
    READ_A(bufA, 0, aF);
    READ_W(bufW, 0, bLo);
    LG0; FENCE;
    MMAC(0, 0, aF, bLo); FENCE;
    VM2; BARRIER;
    READ_W(bufW, 1, bHi);
    LG0; FENCE;
    MMAC(0, 1, aF, bHi); FENCE;
    VM0; BARRIER;
    READ_A(bufA, 1, aF);
    LG0; FENCE;
    MMAC(1, 0, aF, bLo); FENCE;
    MMAC(1, 1, aF, bHi);
  }

  // ---- fused epilogue ----
  // C/D layout: col = lane&15, row = (lane>>4)*4 + reg   [m89/m91]
  const int lr = (l >> 4) * 4;
  const int lc = l & 15;
  const int hc = nrow0 + wh * 16 + lc;
  const float bzi = biasC[0 * 512 + hc];
  const float bzf = biasC[1 * 512 + hc];
  const float bzg = biasC[2 * 512 + hc];
  const float bzo = biasC[3 * 512 + hc];
#pragma unroll
  for (int mf = 0; mf < 8; ++mf) {
#pragma unroll
    for (int j = 0; j < 4; ++j) {
      const int row = rowA0 + wm * 128 + mf * 16 + lr + j;
      const float zi = acc[0][mf][j] + bzi;
      const float zf = acc[1][mf][j] + bzf;
      const float zg = acc[2][mf][j] + bzg;
      const float zo = acc[3][mf][j] + bzo;
      const float ig = sigmoidf_(zi);
      const float fg = sigmoidf_(zf);
      const float gg = tanhf_(zg);
      const float og = sigmoidf_(zo);
      const size_t idx = (size_t)row * 512 + hc;
      const float cv = c[idx];
      const float cn = fg * cv + ig * gg;
      const float hn = og * tanhf_(cn);
      outh[idx] = hn;
      outc[idx] = cn;
    }
  }
}

// ---------- fallback: proven R2 kernel ----------
__launch_bounds__(256, 2)
__global__ void lstm_legacy_kernel(Params p) {
  __shared__ char smem[32768];
  __shared__ float biasLDS[4][32];

  const int tid = threadIdx.x;
  const int w   = tid >> 6;
  const int l   = tid & 63;
  const int m_tile = blockIdx.x & 127;
  const int h_tile = blockIdx.x >> 7;

  char* smemA = smem;
  char* smemW = smem + 16384;
  const int rowA0 = m_tile * 128;
  const int nrow0 = h_tile * 32;

  if (tid < 128) {
    const int g = tid >> 5, hh = tid & 31;
    const int hcb = nrow0 + hh;
    biasLDS[g][hh] = p.bW[g][hcb] + p.bE[g][hcb];
  }

  const int sr = tid >> 3;
  const int sc = tid & 7;
  const int wcol = (sc * 16) ^ ((sr & 7) << 4);

  f32x4 acc[4][2][2] = {};
  f32x4 rg[16];

  auto load_tile = [&](int kt) {
    const float* sA = (kt < 8) ? p.u : p.h;
    const int kc = (kt & 7) * 64;
#pragma unroll
    for (int cc = 0; cc < 4; ++cc) {
      const float* gp = sA + (size_t)(rowA0 + cc * 32 + sr) * 512 + kc + sc * 8;
      rg[cc * 2]     = *(const f32x4*)gp;
      rg[cc * 2 + 1] = *(const f32x4*)(gp + 4);
    }
#pragma unroll
    for (int cc = 0; cc < 4; ++cc) {
      const float* sW = (kt < 8) ? p.W[cc] : p.U[cc];
      const float* gp = sW + (size_t)(nrow0 + sr) * 512 + kc + sc * 8;
      rg[8 + cc * 2]     = *(const f32x4*)gp;
      rg[8 + cc * 2 + 1] = *(const f32x4*)(gp + 4);
    }
  };

  auto write_tile = [&]() {
#pragma unroll
    for (int cc = 0; cc < 4; ++cc)
      *(bf16x8*)(smemA + (cc * 32 + sr) * 128 + wcol) = cvt8(rg[cc * 2], rg[cc * 2 + 1]);
#pragma unroll
    for (int cc = 0; cc < 4; ++cc)
      *(bf16x8*)(smemW + (cc * 32 + sr) * 128 + wcol) = cvt8(rg[8 + cc * 2], rg[8 + cc * 2 + 1]);
  };

  const int xr = (l & 7) << 4;

  auto compute = [&]() {
#pragma unroll
    for (int kk = 0; kk < 2; ++kk) {
      const int kb = (kk * 64 + (l >> 4) * 16) ^ xr;
      bf16x8 a0 = *(const bf16x8*)(smemA + (w * 32 +      (l & 15)) * 128 + kb);
      bf16x8 a1 = *(const bf16x8*)(smemA + (w * 32 + 16 + (l & 15)) * 128 + kb);
#pragma unroll
      for (int g = 0; g < 4; ++g) {
#pragma unroll
        for (int ni = 0; ni < 2; ++ni) {
          bf16x8 b = *(const bf16x8*)(smemW + (g * 32 + ni * 16 + (l & 15)) * 128 + kb);
          acc[g][0][ni] = __builtin_amdgcn_mfma_f32_16x16x32_bf16(a0, b, acc[g][0][ni], 0, 0, 0);
          acc[g][1][ni] = __builtin_amdgcn_mfma_f32_16x16x32_bf16(a1, b, acc[g][1][ni], 0, 0, 0);
        }
      }
    }
  };

  load_tile(0);
  for (int kt = 0; kt < 16; ++kt) {
    write_tile();
    __syncthreads();
    if (kt < 15) load_tile(kt + 1);
    compute();
    __syncthreads();
  }

  const int lr = (l >> 4) * 4;
  const int lc = l & 15;
#pragma unroll
  for (int mi = 0; mi < 2; ++mi) {
#pragma unroll
    for (int j = 0; j < 4; ++j) {
      const int row = rowA0 + w * 32 + mi * 16 + lr + j;
#pragma unroll
      for (int ni = 0; ni < 2; ++ni) {
        const int hcc = nrow0 + ni * 16 + lc;
        const int bcol = ni * 16 + lc;
        const float zi = acc[0][mi][ni][j] + biasLDS[0][bcol];
        const float zf = acc[1][mi][ni][j] + biasLDS[1][bcol];
        const float zg = acc[2][mi][ni][j] + biasLDS[2][bcol];
        const float zo = acc[3][mi][ni][j] + biasLDS[3][bcol];
        const float ig = sigmoidf_(zi);
        const float fg = sigmoidf_(zf);
        const float gg = tanhf_(zg);
        const float og = sigmoidf_(zo);
        const size_t idx = (size_t)row * 512 + hcc;
        const float cv = p.c[idx];
        const float cn = fg * cv + ig * gg;
        const float hn = og * tanhf_(cn);
        p.outh[idx] = hn;
        p.outc[idx] = cn;
      }
    }
  }
}

extern "C" void kernel_launch(void* const* d_in, const int* in_sizes, int n_in,
                              void* d_out, int out_size, void* d_ws, size_t ws_size,
                              hipStream_t stream) {
  Params p;
  p.u = (const float*)d_in[0];
  p.h = (const float*)d_in[1];
  p.c = (const float*)d_in[2];
  p.W[0] = (const float*)d_in[3];
  p.bW[0] = (const float*)d_in[4];
  p.W[1] = (const float*)d_in[5];
  p.bW[1] = (const float*)d_in[6];
  p.W[2] = (const float*)d_in[7];
  p.bW[2] = (const float*)d_in[8];
  p.W[3] = (const float*)d_in[9];
  p.bW[3] = (const float*)d_in[10];
  p.U[0] = (const float*)d_in[11];
  p.U[1] = (const float*)d_in[12];
  p.U[2] = (const float*)d_in[13];
  p.U[3] = (const float*)d_in[14];
  p.bE[0] = (const float*)d_in[15];
  p.bE[1] = (const float*)d_in[16];
  p.bE[2] = (const float*)d_in[17];
  p.bE[3] = (const float*)d_in[18];
  p.outh = (float*)d_out;
  p.outc = (float*)d_out + (size_t)BDIM * HDIM;

  const size_t X_BYTES = (size_t)BDIM * 1024 * 2;        // 32 MB
  const size_t W_BYTES = (size_t)4 * 512 * 1024 * 2;     // 4 MB
  const size_t B_BYTES = 2048 * 4;                       // 8 KB
  if (ws_size >= X_BYTES + W_BYTES + B_BYTES) {
    __hip_bfloat16* Xbf = (__hip_bfloat16*)d_ws;
    __hip_bfloat16* Wbf = (__hip_bfloat16*)((char*)d_ws + X_BYTES);
    float* biasC = (float*)((char*)d_ws + X_BYTES + W_BYTES);

    hipLaunchKernelGGL(cvt_x_kernel, dim3(4096), dim3(512), 0, stream, p.u, p.h, Xbf);
    hipLaunchKernelGGL(cvt_w_kernel, dim3(512), dim3(512), 0, stream, p, Wbf, biasC);
    hipLaunchKernelGGL(lstm_main_kernel, dim3(512), dim3(512), 0, stream,
                       Xbf, Wbf, biasC, p.c, p.outh, p.outc);
  } else {
    hipLaunchKernelGGL(lstm_legacy_kernel, dim3(2048), dim3(256), 0, stream, p);
  }
}